// Round 11
// baseline (157.640 us; speedup 1.0000x reference)
//
#include <hip/hip_runtime.h>
#include <hip/hip_bf16.h>

#define NB 2
#define NN 20000
#define NKN 16          // neighbors per node
#define NC 128          // C_IN
#define NM 9            // M kernels
#define NO 128          // C_OUT
#define NR (NB*NN)      // 40000 rows
#define KK (NM*NC)      // 1152 GEMM reduce dim
#define NKC (KK/32)     // 36 K-chunks of 32
#define NPB 16          // nodes per fused block
#define YS 12           // padded y row stride (floats) -> float4-aligned
#define QS (NKN*12+4)   // per-node q stride (floats): ≡4 mod 32 banks -> conflict-free
#define YB (NR/64)      // ycalc blocks (64 nodes each) = 625

typedef short bf16x8 __attribute__((ext_vector_type(8)));
typedef float f32x4 __attribute__((ext_vector_type(4)));
typedef float f32x2 __attribute__((ext_vector_type(2)));
typedef unsigned short u16x8 __attribute__((ext_vector_type(8)));
typedef unsigned short u16x4 __attribute__((ext_vector_type(4)));

__device__ inline f32x2 bfpair(unsigned int w) {   // [lo16, hi16] bf16 -> float2
    union { unsigned int u; float f; } lo, hi;
    lo.u = w << 16; hi.u = w & 0xFFFF0000u;
    return (f32x2){lo.f, hi.f};
}

// ---------------- Kernel 1: prep (unchanged from R10) ----------------
__global__ __launch_bounds__(256) void prep_kernel(const float* __restrict__ x,
                                                   const float* __restrict__ u,
                                                   const float* __restrict__ W,
                                                   float* __restrict__ y,
                                                   __hip_bfloat16* __restrict__ xb,
                                                   __hip_bfloat16* __restrict__ Wg,
                                                   int use_xb) {
    int tid = threadIdx.x;
    if (blockIdx.x < YB) {
        int wave = tid >> 6, lane = tid & 63;
        int lr = lane & 15, quad = lane >> 4;
        int node0 = blockIdx.x * 64 + wave * 16;
        long xbase = (long)(node0 + lr) * NC;

        bf16x8 afr[4];
        #pragma unroll
        for (int kc = 0; kc < 4; kc++) {
            const float* px = x + xbase + kc * 32 + quad * 8;
            float4 a0 = *(const float4*)px;
            float4 a1 = *(const float4*)(px + 4);
            union { bf16x8 v; unsigned short s[8]; __hip_bfloat16 h[8]; } af;
            af.h[0] = __float2bfloat16(a0.x); af.h[1] = __float2bfloat16(a0.y);
            af.h[2] = __float2bfloat16(a0.z); af.h[3] = __float2bfloat16(a0.w);
            af.h[4] = __float2bfloat16(a1.x); af.h[5] = __float2bfloat16(a1.y);
            af.h[6] = __float2bfloat16(a1.z); af.h[7] = __float2bfloat16(a1.w);
            afr[kc] = af.v;
            if (use_xb)
                *(u16x8*)((unsigned short*)xb + xbase + kc * 32 + quad * 8) =
                    *(u16x8*)&af.v;
        }
        int cs = (lr < NM) ? lr : 0;
        float fz = (lr < NM) ? 1.f : 0.f;
        f32x4 acc = (f32x4){0.f, 0.f, 0.f, 0.f};
        #pragma unroll
        for (int kc = 0; kc < 4; kc++) {
            const float* pu = u + cs * NC + kc * 32 + quad * 8;
            float4 b0 = *(const float4*)pu;
            float4 b1 = *(const float4*)(pu + 4);
            union { bf16x8 v; __hip_bfloat16 h[8]; } bf;
            bf.h[0] = __float2bfloat16(b0.x * fz); bf.h[1] = __float2bfloat16(b0.y * fz);
            bf.h[2] = __float2bfloat16(b0.z * fz); bf.h[3] = __float2bfloat16(b0.w * fz);
            bf.h[4] = __float2bfloat16(b1.x * fz); bf.h[5] = __float2bfloat16(b1.y * fz);
            bf.h[6] = __float2bfloat16(b1.z * fz); bf.h[7] = __float2bfloat16(b1.w * fz);
            acc = __builtin_amdgcn_mfma_f32_16x16x32_bf16(afr[kc], bf.v, acc, 0, 0, 0);
        }
        if (lr < NM) {
            #pragma unroll
            for (int r = 0; r < 4; r++)
                y[(long)(node0 + quad * 4 + r) * YS + lr] = acc[r];
        }
    } else {
        int t = (blockIdx.x - YB) * 256 + tid;   // t < 1152*128
        int kk = t >> 7;
        int o = t & 127;
        int m = kk >> 7;
        int c = kk & 127;
        float v = W[m * 16384 + o * 128 + c];
        Wg[((kk >> 5) * 128 + o) * 32 + (kk & 31)] = __float2bfloat16(v);
    }
}

// ---------------- Kernel 2: fused, 512 threads, 4 channels/thread --------------
// Block = 16 nodes, 512 threads (8 waves), 36,864 B LDS, pinned 4 waves/EU:
// 2 blocks/CU = 16 waves/CU with a 128-VGPR budget -> all 16 gathers batch.
// thread = (ln = tid>>5, k = (tid>>1)&15, h = tid&1); channels c4 = (2k+h)*4.
template<bool BF16G>
__global__ __launch_bounds__(512)
__attribute__((amdgpu_waves_per_eu(4, 4)))
void fused_kernel(const float* __restrict__ x,
                  const __hip_bfloat16* __restrict__ xb,
                  const int* __restrict__ adj,
                  const float* __restrict__ y,
                  const float* __restrict__ cv,
                  const __hip_bfloat16* __restrict__ Wg,
                  const float* __restrict__ bv,
                  float* __restrict__ out) {
    __shared__ __align__(16) short s_S[NPB * KK];          // 36,864 B total LDS
    int*   s_adj = (int*)s_S;                              // [NPB*NKN], overlay
    float* s_q   = (float*)((char*)s_S + 1024);            // [NPB*QS],  overlay

    int tid = threadIdx.x;
    int node0 = blockIdx.x * NPB;
    int b = node0 / NN;
    int n0 = node0 - b * NN;
    int ln = tid >> 5;                                     // node 0..15
    int k  = (tid >> 1) & 15;                              // edge 0..15
    int h  = tid & 1;                                      // channel half

    // ---- A1: adj + y row loads (drained by bar1) ----
    int a = adj[(n0 + ln) * NKN + k];
    const float* yn = y + (long)(node0 + ln) * YS;
    const float* ya = y + (long)(b * NN + ((a > 0) ? a - 1 : 0)) * YS;
    float4 yn0 = *(const float4*)yn;
    float4 yn1 = *(const float4*)(yn + 4);
    float  yn8 = yn[8];
    float4 ya0 = *(const float4*)ya;
    float4 ya1 = *(const float4*)(ya + 4);
    float  ya8 = ya[8];
    if (h == 0) s_adj[ln * NKN + k] = a;
    __syncthreads();                                       // bar1

    // ---- idx/deg; issue ALL 16 gathers (batched: ~110 VGPRs live) ----
    int c4 = (2 * k + h) * 4;                              // 4-channel base
    int idx[NKN]; int d = 0;
    #pragma unroll
    for (int j = 0; j < NKN; j++) {
        int aa = s_adj[ln * NKN + j];
        d += (aa > 0);
        idx[j] = (aa > 0) ? aa - 1 : 0;                    // safe index; q=0 kills it
    }
    float di = (d > 0) ? 1.f / (float)d : 0.f;

    uint2 pw[NKN];
    if (BF16G) {
        #pragma unroll
        for (int j = 0; j < NKN; j++)
            pw[j] = *(const uint2*)((const unsigned short*)xb +
                                    (long)(b * NN + idx[j]) * NC + c4);
    }

    // ---- A2: softmax on pre-loaded y (overlaps gather latency) ----
    {
        float sel = (a > 0) ? 1.f : 0.f;
        float l[NM];
        l[0] = yn0.x - sel * ya0.x + cv[0];
        l[1] = yn0.y - sel * ya0.y + cv[1];
        l[2] = yn0.z - sel * ya0.z + cv[2];
        l[3] = yn0.w - sel * ya0.w + cv[3];
        l[4] = yn1.x - sel * ya1.x + cv[4];
        l[5] = yn1.y - sel * ya1.y + cv[5];
        l[6] = yn1.z - sel * ya1.z + cv[6];
        l[7] = yn1.w - sel * ya1.w + cv[7];
        l[8] = yn8   - sel * ya8   + cv[8];
        float mx = l[0];
        #pragma unroll
        for (int m = 1; m < NM; m++) mx = fmaxf(mx, l[m]);
        float e[NM]; float sum = 0.f;
        #pragma unroll
        for (int m = 0; m < NM; m++) { e[m] = expf(l[m] - mx); sum += e[m]; }
        float qs = (a > 0) ? (1.f / sum) : 0.f;
        if (h == 0) {
            #pragma unroll
            for (int m = 0; m < NM; m++) s_q[ln * QS + k * 12 + m] = e[m] * qs;
        }
    }
    __syncthreads();                                       // bar2: q ready, gathers drained

    // ---- A3: accumulate 16 neighbors x 4 channels (f32x2 packed FMA) ----
    f32x2 s2[NM][2];
    #pragma unroll
    for (int m = 0; m < NM; m++) {
        s2[m][0] = (f32x2){0.f, 0.f};
        s2[m][1] = (f32x2){0.f, 0.f};
    }

    #define ACC_ALL(P0, P1, J) {                                              \
        const float* qr = &s_q[ln * QS + (J) * 12];                           \
        float4 qa = *(const float4*)qr;                                       \
        float4 qb = *(const float4*)(qr + 4);                                 \
        float  q8 = qr[8];                                                    \
        f32x2 qq;                                                             \
        qq=(f32x2){qa.x,qa.x}; s2[0][0]+=qq*P0; s2[0][1]+=qq*P1;              \
        qq=(f32x2){qa.y,qa.y}; s2[1][0]+=qq*P0; s2[1][1]+=qq*P1;              \
        qq=(f32x2){qa.z,qa.z}; s2[2][0]+=qq*P0; s2[2][1]+=qq*P1;              \
        qq=(f32x2){qa.w,qa.w}; s2[3][0]+=qq*P0; s2[3][1]+=qq*P1;              \
        qq=(f32x2){qb.x,qb.x}; s2[4][0]+=qq*P0; s2[4][1]+=qq*P1;              \
        qq=(f32x2){qb.y,qb.y}; s2[5][0]+=qq*P0; s2[5][1]+=qq*P1;              \
        qq=(f32x2){qb.z,qb.z}; s2[6][0]+=qq*P0; s2[6][1]+=qq*P1;              \
        qq=(f32x2){qb.w,qb.w}; s2[7][0]+=qq*P0; s2[7][1]+=qq*P1;              \
        qq=(f32x2){q8,q8};     s2[8][0]+=qq*P0; s2[8][1]+=qq*P1; }

    if (BF16G) {
        #pragma unroll
        for (int j = 0; j < NKN; j++) {
            f32x2 p0 = bfpair(pw[j].x), p1 = bfpair(pw[j].y);
            ACC_ALL(p0, p1, j)
        }
    } else {
        #pragma unroll
        for (int j = 0; j < NKN; j++) {
            float4 fa = *(const float4*)(x + (long)(b * NN + idx[j]) * NC + c4);
            f32x2 p0 = (f32x2){fa.x, fa.y}, p1 = (f32x2){fa.z, fa.w};
            ACC_ALL(p0, p1, j)
        }
    }
    #undef ACC_ALL
    __syncthreads();                                       // bar2.5: q/adj now dead

    // ---- pack + write S' (4 ch -> u16x4) into (now-free) s_S, XOR-swizzled ----
    #pragma unroll
    for (int m = 0; m < NM; m++) {
        u16x4 ov;
        union { unsigned short hh; __hip_bfloat16 bb; } c0, c1, c2, c3;
        c0.bb = __float2bfloat16(s2[m][0][0] * di);
        c1.bb = __float2bfloat16(s2[m][0][1] * di);
        c2.bb = __float2bfloat16(s2[m][1][0] * di);
        c3.bb = __float2bfloat16(s2[m][1][1] * di);
        ov[0] = c0.hh; ov[1] = c1.hh; ov[2] = c2.hh; ov[3] = c3.hh;
        int g = m * 16 + k;                                // 16B granule index in row
        int gs = g ^ (ln & 7);                             // XOR swizzle
        *(u16x4*)(&s_S[ln * KK + gs * 8 + h * 4]) = ov;
    }
    __syncthreads();                                       // bar3: S' ready

    // ---------------- phase B: GEMM 16x1152 @ 1152x128; wave = 1 col-tile ----------
    int wave = tid >> 6;                                   // col-tile 0..7
    int lane = tid & 63;
    int lr = lane & 15;
    int quad = lane >> 4;
    const short* wg = reinterpret_cast<const short*>(Wg);
    f32x4 acc = (f32x4){0.f, 0.f, 0.f, 0.f};

    #pragma unroll 12
    for (int kc = 0; kc < NKC; kc++) {
        int g = kc * 4 + quad;
        int gs = g ^ (lr & 7);
        bf16x8 afrag = *(const bf16x8*)(&s_S[lr * KK + gs * 8]);
        bf16x8 bfrag = *(const bf16x8*)(wg + ((kc * 128) + wave * 16 + lr) * 32 + quad * 8);
        acc = __builtin_amdgcn_mfma_f32_16x16x32_bf16(afrag, bfrag, acc, 0, 0, 0);
    }

    // epilogue: D row = quad*4 + r, col = wave*16 + lr
    int col = wave * 16 + lr;
    float bb = bv[col];
    int rbase = node0 + quad * 4;
    #pragma unroll
    for (int r = 0; r < 4; r++)
        out[(long)(rbase + r) * NO + col] = acc[r] + bb;
}

extern "C" void kernel_launch(void* const* d_in, const int* in_sizes, int n_in,
                              void* d_out, int out_size, void* d_ws, size_t ws_size,
                              hipStream_t stream) {
    const float* x   = (const float*)d_in[0];   // (B,N,C)
    const int*   adj = (const int*)  d_in[1];   // (N,K)
    const float* W   = (const float*)d_in[2];   // (M,O,C)
    const float* bv  = (const float*)d_in[3];   // (O,)
    const float* u   = (const float*)d_in[4];   // (M,C)
    const float* cv  = (const float*)d_in[5];   // (M,)
    float* out = (float*)d_out;

    char* ws = (char*)d_ws;
    float* y = (float*)ws;                                     // 40000*12*4 = 1,920,000 B
    __hip_bfloat16* Wg = (__hip_bfloat16*)(ws + 1920000);      //   294,912 B
    __hip_bfloat16* xb = (__hip_bfloat16*)(ws + 2214912);      // 10,240,000 B (16B-aligned)
    bool use_xb = (ws_size >= (size_t)12454912);

    prep_kernel<<<YB + 576, 256, 0, stream>>>(x, u, W, y, use_xb ? xb : nullptr, Wg,
                                              use_xb ? 1 : 0);
    if (use_xb)
        fused_kernel<true><<<NR / NPB, 512, 0, stream>>>(x, xb, adj, y, cv, Wg, bv, out);
    else
        fused_kernel<false><<<NR / NPB, 512, 0, stream>>>(x, xb, adj, y, cv, Wg, bv, out);
}

// Round 12
// 133.018 us; speedup vs baseline: 1.1851x; 1.1851x over previous
//
#include <hip/hip_runtime.h>
#include <hip/hip_bf16.h>

#define NB 2
#define NN 20000
#define NKN 16          // neighbors per node
#define NC 128          // C_IN
#define NM 9            // M kernels
#define NO 128          // C_OUT
#define NR (NB*NN)      // 40000 rows
#define KK (NM*NC)      // 1152 GEMM reduce dim
#define NKC (KK/32)     // 36 K-chunks of 32
#define NPB 32          // nodes per fused block (20000 % 32 == 0 -> no batch straddle)
#define YS 12           // padded y row stride (floats) -> float4-aligned
#define QS (NKN*12+4)   // per-node q stride (floats): ≡4 mod 32 banks -> conflict-free
#define YB (NR/64)      // ycalc blocks (64 nodes each) = 625

typedef short bf16x8 __attribute__((ext_vector_type(8)));
typedef float f32x4 __attribute__((ext_vector_type(4)));
typedef float f32x2 __attribute__((ext_vector_type(2)));
typedef unsigned short u16x8 __attribute__((ext_vector_type(8)));

__device__ inline f32x2 bfpair(unsigned int w) {   // [lo16, hi16] bf16 -> float2
    union { unsigned int u; float f; } lo, hi;
    lo.u = w << 16; hi.u = w & 0xFFFF0000u;
    return (f32x2){lo.f, hi.f};
}

// ---------------- Kernel 1: prep (unchanged from R10) ----------------
__global__ __launch_bounds__(256) void prep_kernel(const float* __restrict__ x,
                                                   const float* __restrict__ u,
                                                   const float* __restrict__ W,
                                                   float* __restrict__ y,
                                                   __hip_bfloat16* __restrict__ xb,
                                                   __hip_bfloat16* __restrict__ Wg,
                                                   int use_xb) {
    int tid = threadIdx.x;
    if (blockIdx.x < YB) {
        int wave = tid >> 6, lane = tid & 63;
        int lr = lane & 15, quad = lane >> 4;
        int node0 = blockIdx.x * 64 + wave * 16;
        long xbase = (long)(node0 + lr) * NC;

        bf16x8 afr[4];
        #pragma unroll
        for (int kc = 0; kc < 4; kc++) {
            const float* px = x + xbase + kc * 32 + quad * 8;
            float4 a0 = *(const float4*)px;
            float4 a1 = *(const float4*)(px + 4);
            union { bf16x8 v; unsigned short s[8]; __hip_bfloat16 h[8]; } af;
            af.h[0] = __float2bfloat16(a0.x); af.h[1] = __float2bfloat16(a0.y);
            af.h[2] = __float2bfloat16(a0.z); af.h[3] = __float2bfloat16(a0.w);
            af.h[4] = __float2bfloat16(a1.x); af.h[5] = __float2bfloat16(a1.y);
            af.h[6] = __float2bfloat16(a1.z); af.h[7] = __float2bfloat16(a1.w);
            afr[kc] = af.v;
            if (use_xb)
                *(u16x8*)((unsigned short*)xb + xbase + kc * 32 + quad * 8) =
                    *(u16x8*)&af.v;
        }
        int cs = (lr < NM) ? lr : 0;
        float fz = (lr < NM) ? 1.f : 0.f;
        f32x4 acc = (f32x4){0.f, 0.f, 0.f, 0.f};
        #pragma unroll
        for (int kc = 0; kc < 4; kc++) {
            const float* pu = u + cs * NC + kc * 32 + quad * 8;
            float4 b0 = *(const float4*)pu;
            float4 b1 = *(const float4*)(pu + 4);
            union { bf16x8 v; __hip_bfloat16 h[8]; } bf;
            bf.h[0] = __float2bfloat16(b0.x * fz); bf.h[1] = __float2bfloat16(b0.y * fz);
            bf.h[2] = __float2bfloat16(b0.z * fz); bf.h[3] = __float2bfloat16(b0.w * fz);
            bf.h[4] = __float2bfloat16(b1.x * fz); bf.h[5] = __float2bfloat16(b1.y * fz);
            bf.h[6] = __float2bfloat16(b1.z * fz); bf.h[7] = __float2bfloat16(b1.w * fz);
            acc = __builtin_amdgcn_mfma_f32_16x16x32_bf16(afr[kc], bf.v, acc, 0, 0, 0);
        }
        if (lr < NM) {
            #pragma unroll
            for (int r = 0; r < 4; r++)
                y[(long)(node0 + quad * 4 + r) * YS + lr] = acc[r];
        }
    } else {
        int t = (blockIdx.x - YB) * 256 + tid;   // t < 1152*128
        int kk = t >> 7;
        int o = t & 127;
        int m = kk >> 7;
        int c = kk & 127;
        float v = W[m * 16384 + o * 128 + c];
        Wg[((kk >> 5) * 128 + o) * 32 + (kk & 31)] = __float2bfloat16(v);
    }
}

// ---------------- Kernel 2: fused, NPB=32, 512 threads (R10 per-thread shape) -------
// Block = 32 nodes, 512 threads (8 waves), 73,728 B LDS -> 2 blocks/CU (16 waves).
// Phase A identical per-thread to R10 (thread = node x 8-channel owner, uint4 gathers).
// Phase B: 8 waves x 1 col-tile x 2 row-tiles: B-frag loaded ONCE per kc, 2 MFMAs
//   -> Wg L2 traffic per node halved vs NPB=16.
// LDS OVERLAY: s_adj + s_q live in s_S region (dead before s_S's first write).
template<bool BF16G>
__global__ __launch_bounds__(512, 4) void fused_kernel(const float* __restrict__ x,
                                                       const __hip_bfloat16* __restrict__ xb,
                                                       const int* __restrict__ adj,
                                                       const float* __restrict__ y,
                                                       const float* __restrict__ cv,
                                                       const __hip_bfloat16* __restrict__ Wg,
                                                       const float* __restrict__ bv,
                                                       float* __restrict__ out) {
    __shared__ __align__(16) short s_S[NPB * KK];          // 73,728 B total LDS
    int*   s_adj = (int*)s_S;                              // [NPB*NKN] = 2048 B, overlay
    float* s_q   = (float*)((char*)s_S + 2048);            // [NPB*QS] = 25,088 B, overlay

    int tid = threadIdx.x;
    int node0 = blockIdx.x * NPB;
    int b = node0 / NN;
    int n0 = node0 - b * NN;
    int ln = tid >> 4, k = tid & 15;                       // 512 = 32 nodes x 16 edges

    // ---- A1: own adj element + y row loads (drained by bar1) ----
    int a = adj[(n0 + ln) * NKN + k];
    const float* yn = y + (long)(node0 + ln) * YS;
    const float* ya = y + (long)(b * NN + ((a > 0) ? a - 1 : 0)) * YS;
    float4 yn0 = *(const float4*)yn;
    float4 yn1 = *(const float4*)(yn + 4);
    float  yn8 = yn[8];
    float4 ya0 = *(const float4*)ya;
    float4 ya1 = *(const float4*)(ya + 4);
    float  ya8 = ya[8];
    s_adj[ln * NKN + k] = a;
    __syncthreads();                                       // bar1

    // ---- idx/deg; issue gather batch 0 (in flight through softmax) ----
    int c8 = k << 3;
    int idx[NKN]; int d = 0;
    #pragma unroll
    for (int j = 0; j < NKN; j++) {
        int aa = s_adj[ln * NKN + j];
        d += (aa > 0);
        idx[j] = (aa > 0) ? aa - 1 : 0;                    // safe index; q=0 kills it
    }
    float di = (d > 0) ? 1.f / (float)d : 0.f;

    uint4 pw0[8];
    if (BF16G) {
        #pragma unroll
        for (int j = 0; j < 8; j++)
            pw0[j] = *(const uint4*)((const unsigned short*)xb +
                                     (long)(b * NN + idx[j]) * NC + c8);
    }

    // ---- A2: softmax on pre-loaded y; q pre-zeroed for padding edges ----
    {
        float sel = (a > 0) ? 1.f : 0.f;
        float l[NM];
        l[0] = yn0.x - sel * ya0.x + cv[0];
        l[1] = yn0.y - sel * ya0.y + cv[1];
        l[2] = yn0.z - sel * ya0.z + cv[2];
        l[3] = yn0.w - sel * ya0.w + cv[3];
        l[4] = yn1.x - sel * ya1.x + cv[4];
        l[5] = yn1.y - sel * ya1.y + cv[5];
        l[6] = yn1.z - sel * ya1.z + cv[6];
        l[7] = yn1.w - sel * ya1.w + cv[7];
        l[8] = yn8   - sel * ya8   + cv[8];
        float mx = l[0];
        #pragma unroll
        for (int m = 1; m < NM; m++) mx = fmaxf(mx, l[m]);
        float e[NM]; float sum = 0.f;
        #pragma unroll
        for (int m = 0; m < NM; m++) { e[m] = expf(l[m] - mx); sum += e[m]; }
        float qs = (a > 0) ? (1.f / sum) : 0.f;
        #pragma unroll
        for (int m = 0; m < NM; m++) s_q[ln * QS + k * 12 + m] = e[m] * qs;
    }
    __syncthreads();                                       // bar2: q ready

    // ---- A3: issue batch 1, then accumulate both batches (f32x2 packed FMA) ----
    f32x2 s2[NM][4];
    #pragma unroll
    for (int m = 0; m < NM; m++)
        #pragma unroll
        for (int j = 0; j < 4; j++) s2[m][j] = (f32x2){0.f, 0.f};

    #define ACC_ALL(P0, P1, P2, P3, KK2) {                                    \
        const float* qr = &s_q[ln * QS + (KK2) * 12];                         \
        float4 qa = *(const float4*)qr;                                       \
        float4 qb = *(const float4*)(qr + 4);                                 \
        float  q8 = qr[8];                                                    \
        f32x2 qq;                                                             \
        qq=(f32x2){qa.x,qa.x}; s2[0][0]+=qq*P0; s2[0][1]+=qq*P1; s2[0][2]+=qq*P2; s2[0][3]+=qq*P3; \
        qq=(f32x2){qa.y,qa.y}; s2[1][0]+=qq*P0; s2[1][1]+=qq*P1; s2[1][2]+=qq*P2; s2[1][3]+=qq*P3; \
        qq=(f32x2){qa.z,qa.z}; s2[2][0]+=qq*P0; s2[2][1]+=qq*P1; s2[2][2]+=qq*P2; s2[2][3]+=qq*P3; \
        qq=(f32x2){qa.w,qa.w}; s2[3][0]+=qq*P0; s2[3][1]+=qq*P1; s2[3][2]+=qq*P2; s2[3][3]+=qq*P3; \
        qq=(f32x2){qb.x,qb.x}; s2[4][0]+=qq*P0; s2[4][1]+=qq*P1; s2[4][2]+=qq*P2; s2[4][3]+=qq*P3; \
        qq=(f32x2){qb.y,qb.y}; s2[5][0]+=qq*P0; s2[5][1]+=qq*P1; s2[5][2]+=qq*P2; s2[5][3]+=qq*P3; \
        qq=(f32x2){qb.z,qb.z}; s2[6][0]+=qq*P0; s2[6][1]+=qq*P1; s2[6][2]+=qq*P2; s2[6][3]+=qq*P3; \
        qq=(f32x2){qb.w,qb.w}; s2[7][0]+=qq*P0; s2[7][1]+=qq*P1; s2[7][2]+=qq*P2; s2[7][3]+=qq*P3; \
        qq=(f32x2){q8,q8};     s2[8][0]+=qq*P0; s2[8][1]+=qq*P1; s2[8][2]+=qq*P2; s2[8][3]+=qq*P3; }

    if (BF16G) {
        uint4 pw1[8];
        #pragma unroll
        for (int j = 0; j < 8; j++)
            pw1[j] = *(const uint4*)((const unsigned short*)xb +
                                     (long)(b * NN + idx[8 + j]) * NC + c8);
        #pragma unroll
        for (int j = 0; j < 8; j++) {
            f32x2 p0 = bfpair(pw0[j].x), p1 = bfpair(pw0[j].y);
            f32x2 p2 = bfpair(pw0[j].z), p3 = bfpair(pw0[j].w);
            ACC_ALL(p0, p1, p2, p3, j)
        }
        #pragma unroll
        for (int j = 0; j < 8; j++) {
            f32x2 p0 = bfpair(pw1[j].x), p1 = bfpair(pw1[j].y);
            f32x2 p2 = bfpair(pw1[j].z), p3 = bfpair(pw1[j].w);
            ACC_ALL(p0, p1, p2, p3, 8 + j)
        }
    } else {
        #pragma unroll
        for (int g = 0; g < NKN / 4; g++) {
            float4 fa[4], fb[4];
            #pragma unroll
            for (int j = 0; j < 4; j++) {
                const float* px = x + (long)(b * NN + idx[g * 4 + j]) * NC + c8;
                fa[j] = *(const float4*)px;
                fb[j] = *(const float4*)(px + 4);
            }
            #pragma unroll
            for (int j = 0; j < 4; j++) {
                f32x2 p0 = (f32x2){fa[j].x, fa[j].y}, p1 = (f32x2){fa[j].z, fa[j].w};
                f32x2 p2 = (f32x2){fb[j].x, fb[j].y}, p3 = (f32x2){fb[j].z, fb[j].w};
                ACC_ALL(p0, p1, p2, p3, g * 4 + j)
            }
        }
    }
    #undef ACC_ALL
    __syncthreads();                                       // bar2.5: q/adj now dead

    // ---- pack + write S' into (now-free) s_S, XOR-swizzled ----
    #pragma unroll
    for (int m = 0; m < NM; m++) {
        u16x8 ov;
        #pragma unroll
        for (int j = 0; j < 4; j++) {
            union { unsigned short h; __hip_bfloat16 bb; } c0, c1;
            c0.bb = __float2bfloat16(s2[m][j][0] * di);
            c1.bb = __float2bfloat16(s2[m][j][1] * di);
            ov[j * 2]     = c0.h;
            ov[j * 2 + 1] = c1.h;
        }
        int g = m * 16 + k;                                // 16B granule index in row
        int gs = g ^ (ln & 7);                             // XOR swizzle
        *(u16x8*)(&s_S[ln * KK + gs * 8]) = ov;
    }
    __syncthreads();                                       // bar3: S' ready

    // -------- phase B: GEMM 32x1152 @ 1152x128; wave = col-tile x 2 row-tiles -------
    int wave = tid >> 6;                                   // col-tile 0..7
    int lane = tid & 63;
    int lr = lane & 15;
    int quad = lane >> 4;
    const short* wg = reinterpret_cast<const short*>(Wg);
    f32x4 acc0 = (f32x4){0.f, 0.f, 0.f, 0.f};              // rows 0..15
    f32x4 acc1 = (f32x4){0.f, 0.f, 0.f, 0.f};              // rows 16..31

    #pragma unroll 9
    for (int kc = 0; kc < NKC; kc++) {
        int g = kc * 4 + quad;
        int gs = g ^ (lr & 7);                             // (16+lr)&7 == lr&7
        bf16x8 bfrag = *(const bf16x8*)(wg + ((kc * 128) + wave * 16 + lr) * 32 + quad * 8);
        bf16x8 a0 = *(const bf16x8*)(&s_S[lr * KK + gs * 8]);
        bf16x8 a1 = *(const bf16x8*)(&s_S[(16 + lr) * KK + gs * 8]);
        acc0 = __builtin_amdgcn_mfma_f32_16x16x32_bf16(a0, bfrag, acc0, 0, 0, 0);
        acc1 = __builtin_amdgcn_mfma_f32_16x16x32_bf16(a1, bfrag, acc1, 0, 0, 0);
    }

    // epilogue: D row = quad*4 + r, col = wave*16 + lr
    int col = wave * 16 + lr;
    float bb = bv[col];
    int rbase = node0 + quad * 4;
    #pragma unroll
    for (int r = 0; r < 4; r++) {
        out[(long)(rbase + r) * NO + col]      = acc0[r] + bb;
        out[(long)(rbase + 16 + r) * NO + col] = acc1[r] + bb;
    }
}

extern "C" void kernel_launch(void* const* d_in, const int* in_sizes, int n_in,
                              void* d_out, int out_size, void* d_ws, size_t ws_size,
                              hipStream_t stream) {
    const float* x   = (const float*)d_in[0];   // (B,N,C)
    const int*   adj = (const int*)  d_in[1];   // (N,K)
    const float* W   = (const float*)d_in[2];   // (M,O,C)
    const float* bv  = (const float*)d_in[3];   // (O,)
    const float* u   = (const float*)d_in[4];   // (M,C)
    const float* cv  = (const float*)d_in[5];   // (M,)
    float* out = (float*)d_out;

    char* ws = (char*)d_ws;
    float* y = (float*)ws;                                     // 40000*12*4 = 1,920,000 B
    __hip_bfloat16* Wg = (__hip_bfloat16*)(ws + 1920000);      //   294,912 B
    __hip_bfloat16* xb = (__hip_bfloat16*)(ws + 2214912);      // 10,240,000 B (16B-aligned)
    bool use_xb = (ws_size >= (size_t)12454912);

    prep_kernel<<<YB + 576, 256, 0, stream>>>(x, u, W, y, use_xb ? xb : nullptr, Wg,
                                              use_xb ? 1 : 0);
    if (use_xb)
        fused_kernel<true><<<NR / NPB, 512, 0, stream>>>(x, xb, adj, y, cv, Wg, bv, out);
    else
        fused_kernel<false><<<NR / NPB, 512, 0, stream>>>(x, xb, adj, y, cv, Wg, bv, out);
}